// Round 3
// baseline (307.154 us; speedup 1.0000x reference)
//
#include <hip/hip_runtime.h>

// Q4_0 quantized linear: out[16, 11008] = x[16, 4096] @ ((w_q-8)*w_scale).T + bias
// All fp32; w_q holds int32 nibble values in [0,16).
//
// Unit-grain split-K GEMV for load balance: each block = ONE unit of
// (1024 output rows x 32 k) = 128 KB of w fetch. Grid 11 x 128 = 1408 blocks,
// 4 co-resident/CU (38.6 KB LDS) -> per-CU HBM fetch equalized to ~5.5 units
// (round-2's 352-block grid left 96 CUs with 2x the streaming of the rest,
// a ~1.4x penalty under the ~24 GB/s per-CU streaming cap).
// R=4 rows/thread amortizes the xs broadcast reads (4 b128 per k feed 64
// FMAs). w packed to bytes in LDS, row stride 36 B (9 words, gcd(9,32)=1 ->
// exactly 2 lanes/bank = free). One barrier per block. Split-K combined with
// fp32 atomicAdd into memset-zeroed out; bias added by the sb==0 blocks.

constexpr int T       = 16;
constexpr int IN      = 4096;
constexpr int OUT     = 11008;
constexpr int NSCALE  = IN / 32;        // 128 scales per row
constexpr int THREADS = 256;
constexpr int R       = 4;              // rows per thread
constexpr int ROWSB   = THREADS * R;    // 1024 rows per block
constexpr int CK      = 32;             // k per block (== Q4_0 block size)
constexpr int WSTRIDE = 36;             // ws8 row stride bytes (32 + 4 pad)
constexpr int XPAD    = 20;             // xs row stride floats (80 B, 16B-aligned)

__global__ __launch_bounds__(THREADS, 4) void qlinear_unit(
    const float* __restrict__ x,        // [T, IN]
    const int*   __restrict__ w_q,      // [OUT, IN]
    const float* __restrict__ w_scale,  // [OUT, NSCALE]
    const float* __restrict__ bias,     // [OUT]
    float* __restrict__ out)            // [T, OUT] (pre-zeroed)
{
    __shared__ __align__(16) float         xs[CK][XPAD];         // 2.5 KiB
    __shared__ __align__(16) unsigned char ws8[ROWSB * WSTRIDE]; // 36 KiB

    const int tid  = threadIdx.x;
    const int row0 = blockIdx.x * ROWSB;     // 0..10
    const int sb   = blockIdx.y;             // scale-block / k-split, 0..127
    const int k0   = sb * CK;

    // ---- stage x chunk transposed: xs[k][t] = x[t][k0+k] ----
    #pragma unroll
    for (int it = 0; it < CK * T / THREADS; ++it) {  // 2
        int idx = it * THREADS + tid;
        int t   = idx >> 5;
        int k   = idx & (CK - 1);
        xs[k][t] = x[t * IN + k0 + k];
    }

    // ---- per-row scale (one Q4_0 block per row in this unit) ----
    float s[R], s8[R];
    #pragma unroll
    for (int r = 0; r < R; ++r) {
        int rg = min(row0 + tid + r * THREADS, OUT - 1);
        float sv = w_scale[rg * NSCALE + sb];
        s[r]  = sv;
        s8[r] = -8.0f * sv;   // exact
    }

    // ---- stage w tile: 1024 rows x 32 ints -> packed bytes in LDS ----
    // flat int4 id f: row rr = f/8, j = f%8; lanes 0..7 read 128 contiguous
    // bytes of one row (coalesced dwordx4 loads).
    #pragma unroll 4
    for (int it = 0; it < (ROWSB * CK / 4) / THREADS; ++it) {  // 32
        int f  = it * THREADS + tid;
        int rr = f >> 3;
        int j  = f & 7;
        int rg = min(row0 + rr, OUT - 1);
        const int4 v = *(const int4*)(w_q + rg * IN + k0 + j * 4);
        unsigned int u = (unsigned)v.x | ((unsigned)v.y << 8) |
                         ((unsigned)v.z << 16) | ((unsigned)v.w << 24);
        *(unsigned int*)(ws8 + rr * WSTRIDE + j * 4) = u;
    }
    __syncthreads();   // single barrier: staging -> compute

    float acc[R][T];
    #pragma unroll
    for (int r = 0; r < R; ++r)
        #pragma unroll
        for (int t = 0; t < T; ++t) acc[r][t] = 0.0f;

    for (int k4 = 0; k4 < CK / 4; ++k4) {      // 8 (rolled: keeps regs low)
        unsigned int q[R];
        #pragma unroll
        for (int r = 0; r < R; ++r)
            q[r] = *(const unsigned int*)(ws8 + (tid + r * THREADS) * WSTRIDE + k4 * 4);

        #pragma unroll
        for (int kk = 0; kk < 4; ++kk) {
            const float4* xp = (const float4*)&xs[k4 * 4 + kk][0];
            float4 x0 = xp[0], x1 = xp[1], x2 = xp[2], x3 = xp[3];
            #pragma unroll
            for (int r = 0; r < R; ++r) {
                // (q - 8) * s with a single rounding; byte extract lowers to
                // v_cvt_f32_ubyte{kk}
                float wv = fmaf((float)((q[r] >> (8 * kk)) & 0xffu), s[r], s8[r]);
                acc[r][0]  = fmaf(wv, x0.x, acc[r][0]);
                acc[r][1]  = fmaf(wv, x0.y, acc[r][1]);
                acc[r][2]  = fmaf(wv, x0.z, acc[r][2]);
                acc[r][3]  = fmaf(wv, x0.w, acc[r][3]);
                acc[r][4]  = fmaf(wv, x1.x, acc[r][4]);
                acc[r][5]  = fmaf(wv, x1.y, acc[r][5]);
                acc[r][6]  = fmaf(wv, x1.z, acc[r][6]);
                acc[r][7]  = fmaf(wv, x1.w, acc[r][7]);
                acc[r][8]  = fmaf(wv, x2.x, acc[r][8]);
                acc[r][9]  = fmaf(wv, x2.y, acc[r][9]);
                acc[r][10] = fmaf(wv, x2.z, acc[r][10]);
                acc[r][11] = fmaf(wv, x2.w, acc[r][11]);
                acc[r][12] = fmaf(wv, x3.x, acc[r][12]);
                acc[r][13] = fmaf(wv, x3.y, acc[r][13]);
                acc[r][14] = fmaf(wv, x3.z, acc[r][14]);
                acc[r][15] = fmaf(wv, x3.w, acc[r][15]);
            }
        }
    }

    // ---- epilogue: bias (split 0 only) + atomic combine across splits ----
    const bool add_b = (sb == 0);
    #pragma unroll
    for (int r = 0; r < R; ++r) {
        int rg = row0 + tid + r * THREADS;
        if (rg < OUT) {
            float b = add_b ? bias[rg] : 0.0f;
            #pragma unroll
            for (int t = 0; t < T; ++t)
                atomicAdd(out + t * OUT + rg, acc[r][t] + b);
        }
    }
}

extern "C" void kernel_launch(void* const* d_in, const int* in_sizes, int n_in,
                              void* d_out, int out_size, void* d_ws, size_t ws_size,
                              hipStream_t stream) {
    const float* x       = (const float*)d_in[0];
    const int*   w_q     = (const int*)d_in[1];
    const float* w_scale = (const float*)d_in[2];
    const float* bias    = (const float*)d_in[3];
    float*       out     = (float*)d_out;

    // Zero the (0xAA-poisoned) output; captured as a graph memset node.
    hipMemsetAsync(d_out, 0, (size_t)out_size * sizeof(float), stream);

    dim3 grid((OUT + ROWSB - 1) / ROWSB, IN / CK);   // 11 x 128 = 1408 blocks
    qlinear_unit<<<grid, THREADS, 0, stream>>>(x, w_q, w_scale, bias, out);
}